// Round 10
// baseline (1667.687 us; speedup 1.0000x reference)
//
#include <hip/hip_runtime.h>
#include <stdint.h>

#define B_   2
#define S_   2048
#define DM   1024
#define FIN  11264
#define DOUT 5120
#define NSH  8
#define DH   128
#define ROWS (B_*S_)

typedef __attribute__((ext_vector_type(8))) __bf16 bf16x8;
typedef __attribute__((ext_vector_type(4))) __bf16 bf16x4;
typedef __attribute__((ext_vector_type(4))) float  f32x4;

union U2 { unsigned int u; __bf16 h[2]; };

__device__ __forceinline__ void gload16(const void* g, void* l) {
    __builtin_amdgcn_global_load_lds((const __attribute__((address_space(1))) void*)g,
                                     (__attribute__((address_space(3))) void*)l, 16, 0, 0);
}

// column permutation: newcol -> original w_in column
__device__ __forceinline__ int origcol(int c) {
    if (c < 3072) { int p = c / 384; return p*1408 + (c - p*384); }
    int q = c - 3072; int p = q >> 10; int w = q & 1023;
    int a = w >> 5, g = (w >> 4) & 1, u = w & 15;
    return p*1408 + 384 + g*512 + a*16 + u;
}

// ---------------- LayerNorm: x f32 (ROWS x DM) -> h bf16 ----------------
__global__ __launch_bounds__(256) void ln_kernel(const float* __restrict__ x,
                                                 const float* __restrict__ sc,
                                                 const float* __restrict__ of,
                                                 __bf16* __restrict__ h) {
    int row = blockIdx.x, t = threadIdx.x;
    const float4 v = *(const float4*)&x[(size_t)row*DM + t*4];
    float s  = v.x + v.y + v.z + v.w;
    float ss = v.x*v.x + v.y*v.y + v.z*v.z + v.w*v.w;
#pragma unroll
    for (int off = 32; off >= 1; off >>= 1) {
        s  += __shfl_xor(s, off);
        ss += __shfl_xor(ss, off);
    }
    __shared__ float rs_[4], rss_[4];
    int wid = t >> 6, lane = t & 63;
    if (lane == 0) { rs_[wid] = s; rss_[wid] = ss; }
    __syncthreads();
    s  = rs_[0] + rs_[1] + rs_[2] + rs_[3];
    ss = rss_[0] + rss_[1] + rss_[2] + rss_[3];
    float mu  = s * (1.f/DM);
    float var = ss * (1.f/DM) - mu*mu;
    float r   = rsqrtf(var + 1e-5f);
    float4 scv = *(const float4*)&sc[t*4];
    float4 ofv = *(const float4*)&of[t*4];
    bf16x4 o;
    o[0] = (__bf16)((v.x-mu)*r*scv.x + ofv.x);
    o[1] = (__bf16)((v.y-mu)*r*scv.y + ofv.y);
    o[2] = (__bf16)((v.z-mu)*r*scv.z + ofv.z);
    o[3] = (__bf16)((v.w-mu)*r*scv.w + ofv.w);
    *(bf16x4*)&h[(size_t)row*DM + t*4] = o;
}

// ------------- transpose+cast: in R x C f32 -> out C x R bf16 (plain) -----------
__global__ __launch_bounds__(256) void transpose_kernel(const float* __restrict__ in,
                                                        __bf16* __restrict__ out,
                                                        int R, int C) {
    __shared__ __bf16 tile[64][72];
    int c0 = blockIdx.x * 64, r0 = blockIdx.y * 64;
    int t = threadIdx.x;
#pragma unroll
    for (int it = 0; it < 4; ++it) {
        int flat = it*1024 + t*4;
        int rl = flat >> 6, cl = flat & 63;
        float4 v = *(const float4*)&in[(size_t)(r0+rl)*C + c0 + cl];
        tile[rl][cl+0] = (__bf16)v.x;
        tile[rl][cl+1] = (__bf16)v.y;
        tile[rl][cl+2] = (__bf16)v.z;
        tile[rl][cl+3] = (__bf16)v.w;
    }
    __syncthreads();
#pragma unroll
    for (int it = 0; it < 4; ++it) {
        int flat = it*1024 + t*4;
        int cl = flat >> 6, rl = flat & 63;
        bf16x4 o;
#pragma unroll
        for (int j = 0; j < 4; ++j) o[j] = tile[rl+j][cl];
        *(bf16x4*)&out[(size_t)(c0+cl)*R + r0 + rl] = o;
    }
}

// ------- transpose+cast with column permutation: w_in (DM x FIN) -> w_in_t [newcol][DM] -------
__global__ __launch_bounds__(256) void transpose_perm_kernel(const float* __restrict__ in,
                                                             __bf16* __restrict__ out) {
    __shared__ __bf16 tile[64][72];
    int c0 = blockIdx.x * 64, r0 = blockIdx.y * 64;
    int t = threadIdx.x;
#pragma unroll
    for (int it = 0; it < 4; ++it) {
        int flat = it*1024 + t*4;
        int rl = flat >> 6, cl = flat & 63;
        int oc = origcol(c0 + cl);
        float4 v = *(const float4*)&in[(size_t)(r0+rl)*FIN + oc];
        tile[rl][cl+0] = (__bf16)v.x;
        tile[rl][cl+1] = (__bf16)v.y;
        tile[rl][cl+2] = (__bf16)v.z;
        tile[rl][cl+3] = (__bf16)v.w;
    }
    __syncthreads();
#pragma unroll
    for (int it = 0; it < 4; ++it) {
        int flat = it*1024 + t*4;
        int cl = flat >> 6, rl = flat & 63;
        bf16x4 o;
#pragma unroll
        for (int j = 0; j < 4; ++j) o[j] = tile[rl+j][cl];
        *(bf16x4*)&out[(size_t)(c0+cl)*DM + r0 + rl] = o;
    }
}

// ---------------- permuted bias ----------------
__global__ __launch_bounds__(256) void permbias_kernel(const float* __restrict__ b_in,
                                                       float* __restrict__ bp) {
    int c = blockIdx.x * 256 + threadIdx.x;
    if (c < FIN) bp[c] = b_in[origcol(c)];
}

// ============ 256x256 single-buffered GEMM (m97 loop, 2 blocks/CU) ============
// BK=64, 8 waves (2Mx4N), LDS 64KB single (A 32K | B 32K), rows 128B XOR-swizzled
// byte^=(row&7)<<4 via pre-swizzled global src. Per K-step: 8 gload -> sync ->
// 24 ds_read_b128 + 64 MFMA -> sync. Cross-block co-residency hides the drain.
// Epilogues: GEMM1 qvk(+bias)->Cqvk, ff->GLU->Cglu; GEMM2 bf16 partials->Cbf[z].
#define MFMA4(ACCI, BN) \
    acc[ACCI][BN] = __builtin_amdgcn_mfma_f32_16x16x32_bf16(a[(ACCI)&3][0], b[BN][0], acc[ACCI][BN],0,0,0); \
    acc[ACCI][BN] = __builtin_amdgcn_mfma_f32_16x16x32_bf16(a[(ACCI)&3][1], b[BN][1], acc[ACCI][BN],0,0,0);

__global__ __launch_bounds__(512, 4) void gemm256s_kernel(const __bf16* __restrict__ A,
                                                          const __bf16* __restrict__ BT,
                                                          const float* __restrict__ bias,
                                                          __bf16* __restrict__ Cqvk,
                                                          __bf16* __restrict__ Cglu,
                                                          __bf16* __restrict__ Cbf,
                                                          int M, int N, int K, int klen) {
    __shared__ __align__(16) char lds[65536];
    int t = threadIdx.x, wid = t >> 6, lane = t & 63;
    int wr = wid >> 2, wc = wid & 3;
    int fr = lane & 15, fq = lane >> 4;
    int kbeg = blockIdx.z * klen;
    int nbx = gridDim.x;
    int bid = blockIdx.y * nbx + blockIdx.x;
    int cpx = (nbx * gridDim.y) >> 3;
    int swz = (bid & 7) * cpx + (bid >> 3);
    int bx = swz % nbx, by = swz / nbx;
    int m0 = by * 256, n0 = bx * 256;

    const __bf16* srcA[4];
    const __bf16* srcB[4];
#pragma unroll
    for (int j = 0; j < 4; ++j) {
        int F = (j*512 + t) * 16;
        int lr = F >> 7, c = (F & 127) ^ ((lr & 7) << 4);
        srcA[j] = A + (size_t)(m0 + lr) * K + kbeg + (c >> 1);
        int row = ((lr >> 5) & 3) * 64 + (lr >> 7) * 32 + (lr & 31);
        srcB[j] = BT + (size_t)(n0 + row) * K + kbeg + (c >> 1);
    }
    int lrAlo[4], lrAhi[4], lrB[4];
#pragma unroll
    for (int i = 0; i < 4; ++i) {
        lrAlo[i] = (wr*128 + i*16 + fr) * 128;
        lrAhi[i] = lrAlo[i] + 64*128;
    }
#pragma unroll
    for (int n = 0; n < 4; ++n)
        lrB[n] = 32768 + ((n >> 1)*128 + wc*32 + (n & 1)*16 + fr) * 128;
    int swzb = (fr & 7) << 4;
    int cb00 = (fq*16) ^ swzb;
    int cb01 = (64 + fq*16) ^ swzb;

    f32x4 acc[8][4] = {};
    for (int k0 = 0; k0 < klen; k0 += 64) {
#pragma unroll
        for (int j = 0; j < 4; ++j)
            gload16(srcA[j] + k0, lds + j*8192 + wid*1024);
#pragma unroll
        for (int j = 0; j < 4; ++j)
            gload16(srcB[j] + k0, lds + 32768 + j*8192 + wid*1024);
        __syncthreads();
        bf16x8 a[4][2], b[4][2];
#pragma unroll
        for (int n = 0; n < 4; ++n) {
            b[n][0] = *(const bf16x8*)(lds + lrB[n] + cb00);
            b[n][1] = *(const bf16x8*)(lds + lrB[n] + cb01);
        }
#pragma unroll
        for (int i = 0; i < 4; ++i) {
            a[i][0] = *(const bf16x8*)(lds + lrAlo[i] + cb00);
            a[i][1] = *(const bf16x8*)(lds + lrAlo[i] + cb01);
        }
#pragma unroll
        for (int i = 0; i < 4; ++i) { MFMA4(i,0) MFMA4(i,1) MFMA4(i,2) MFMA4(i,3) }
#pragma unroll
        for (int i = 0; i < 4; ++i) {
            a[i][0] = *(const bf16x8*)(lds + lrAhi[i] + cb00);
            a[i][1] = *(const bf16x8*)(lds + lrAhi[i] + cb01);
        }
#pragma unroll
        for (int i = 0; i < 4; ++i) { MFMA4(4+i,0) MFMA4(4+i,1) MFMA4(4+i,2) MFMA4(4+i,3) }
        __syncthreads();
    }
    // ---------------- epilogues ----------------
    if (Cbf) {
        __bf16* Cz = Cbf + (size_t)blockIdx.z * M * N;
#pragma unroll
        for (int i = 0; i < 8; ++i)
#pragma unroll
            for (int n = 0; n < 4; ++n) {
                int col = n0 + wc*64 + (n >> 1)*32 + (n & 1)*16 + fr;
#pragma unroll
                for (int r = 0; r < 4; ++r) {
                    int row = m0 + wr*128 + i*16 + fq*4 + r;
                    Cz[(size_t)row*N + col] = (__bf16)acc[i][n][r];
                }
            }
    } else if (n0 < 3072) {
#pragma unroll
        for (int i = 0; i < 8; ++i)
#pragma unroll
            for (int n = 0; n < 4; ++n) {
                int col = n0 + wc*64 + (n >> 1)*32 + (n & 1)*16 + fr;
                float bv = bias[col];
#pragma unroll
                for (int r = 0; r < 4; ++r) {
                    int row = m0 + wr*128 + i*16 + fq*4 + r;
                    Cqvk[(size_t)row*3072 + col] = (__bf16)(acc[i][n][r] + bv);
                }
            }
    } else {
        int q = n0 - 3072;
        int p = q >> 10;
#pragma unroll
        for (int m = 0; m < 2; ++m) {
            int off = wc*64 + m*32;
            float bo = bias[n0 + off + fr];
            float bg = bias[n0 + off + 16 + fr];
            int j = (((q & 1023) + off) >> 5) * 16 + fr;
            int colg = p*640 + 128 + j;
#pragma unroll
            for (int i = 0; i < 8; ++i)
#pragma unroll
                for (int r = 0; r < 4; ++r) {
                    int row = m0 + wr*128 + i*16 + fq*4 + r;
                    float ov = acc[i][2*m][r] + bo;
                    float gv = acc[i][2*m+1][r] + bg;
                    float e2 = __expf(1.5957691216057308f*(gv + 0.044715f*gv*gv*gv));
                    float gl = gv * (1.f - 1.f/(e2 + 1.f));
                    Cglu[(size_t)row*DOUT + colg] = (__bf16)(ov * gl);
                }
        }
    }
}

// ---------------- out = sum of 8 bf16 partials + bias (f32 out) ----------------
__global__ __launch_bounds__(256) void addbias8_kernel(const __bf16* __restrict__ pk,
                                                       const float* __restrict__ bias,
                                                       float* __restrict__ out) {
    int idx = blockIdx.x * 256 + threadIdx.x;       // bf16x4 groups over ROWS*DM
    const size_t stride = (size_t)ROWS * DM / 4;
    float4 s = ((const float4*)bias)[idx & 255];
#pragma unroll
    for (int z = 0; z < 8; ++z) {
        bf16x4 v = ((const bf16x4*)pk)[idx + z*stride];
        s.x += (float)v[0]; s.y += (float)v[1];
        s.z += (float)v[2]; s.w += (float)v[3];
    }
    ((float4*)out)[idx] = s;
}

// ==== fused rope + split + V-transpose: proj2 [ROWS][3072] -> qh, kh, vt ====
__global__ __launch_bounds__(256) void rqkv_kernel(const __bf16* __restrict__ proj2,
                                                   __bf16* __restrict__ qh,
                                                   __bf16* __restrict__ kh,
                                                   __bf16* __restrict__ vt) {
    __shared__ __bf16 tile[64*144];
    int r0 = blockIdx.x * 64;
    int p  = blockIdx.y;
    int t  = threadIdx.x;
    int b  = r0 >> 11;
    int bh = b*NSH + p;
#pragma unroll
    for (int j = 0; j < 4; ++j) {
        int e = (j*256 + t) * 8;
        int sl = e >> 7, d = e & 127;
        const __bf16* rowp = proj2 + (size_t)(r0 + sl)*3072 + p*384;
        bf16x8 vq = *(const bf16x8*)&rowp[d];
        bf16x8 vv = *(const bf16x8*)&rowp[128 + d];
        bf16x8 vk = *(const bf16x8*)&rowp[256 + d];
        int s = (r0 + sl) & (S_ - 1);
        if (d < 64) {
#pragma unroll
            for (int u = 0; u < 4; ++u) {
                int i = (d >> 1) + u;
                float inv = exp2f(-(float)i * 0.4152410118609203f);
                float ang = (float)s * inv;
                float cn = __cosf(ang), sn = __sinf(ang);
                float q0 = vq[2*u], q1 = vq[2*u+1];
                float k0 = vk[2*u], k1 = vk[2*u+1];
                vq[2*u]   = (__bf16)(q0*cn - q1*sn);
                vq[2*u+1] = (__bf16)(q1*cn + q0*sn);
                vk[2*u]   = (__bf16)(k0*cn - k1*sn);
                vk[2*u+1] = (__bf16)(k1*cn + k0*sn);
            }
        }
#pragma unroll
        for (int u = 0; u < 8; ++u) vq[u] = (__bf16)((float)vq[u] * 0.125f);
        size_t o = ((size_t)bh * S_ + s) * DH + d;
        *(bf16x8*)&qh[o] = vq;
        *(bf16x8*)&kh[o] = vk;
        int ch = ((d >> 3) + sl) & 15;
        *(bf16x8*)&tile[sl*144 + ch*8] = vv;
    }
    __syncthreads();
#pragma unroll
    for (int j = 0; j < 4; ++j) {
        int e = (j*256 + t) * 8;
        int d = e >> 6, sb = e & 63;
        bf16x8 o;
#pragma unroll
        for (int u = 0; u < 8; ++u) {
            int sl = sb + u;
            int ch = ((d >> 3) + sl) & 15;
            o[u] = tile[sl*144 + ch*8 + (d & 7)];
        }
        size_t ov = ((size_t)bh * DH + d) * S_ + (r0 & (S_ - 1)) + sb;
        *(bf16x8*)&vt[ov] = o;
    }
}

// ---------------------- flash attention, causal + bias ----------------------
__device__ __forceinline__ void stage_kv(const __bf16* Kb, const __bf16* Vg,
                                         char* KsB, char* VsB,
                                         int kvbase, int t, int wid) {
#pragma unroll
    for (int j = 0; j < 4; ++j) {
        int F = (j*256 + t)*16;
        int r = F >> 8, c = F & 255;
        gload16(Kb + (size_t)(kvbase + r)*DH + ((c ^ ((r & 7) << 4)) >> 1),
                KsB + j*4096 + (wid << 10));
    }
#pragma unroll
    for (int j = 0; j < 4; ++j) {
        int F = (j*256 + t)*16;
        int r = F >> 7, c = F & 127;
        gload16(Vg + (size_t)r*S_ + kvbase + ((c ^ ((r & 7) << 4)) >> 1),
                VsB + j*4096 + (wid << 10));
    }
}

__global__ __launch_bounds__(256, 2) void attn_kernel(const __bf16* __restrict__ qh,
                                                      const __bf16* __restrict__ kh,
                                                      const __bf16* __restrict__ vt,
                                                      const float* __restrict__ ab,
                                                      __bf16* __restrict__ ag) {
    __shared__ __bf16 Ks[2*8192];
    __shared__ __bf16 Vs[2*8192];
    __shared__ __bf16 Ps[4][16*72];
    int bh = blockIdx.y;
    int b = bh >> 3, hh = bh & 7;
    int xr = blockIdx.x;
    int qb = (xr & 1) ? (31 - (xr >> 1)) : (xr >> 1);
    int q0 = qb * 64;
    int t = threadIdx.x, wid = t >> 6, lane = t & 63;
    int fr = lane & 15, fkb = (lane >> 4) * 16;
    const __bf16* Qb = qh + (size_t)bh * S_ * DH;
    const __bf16* Kb = kh + (size_t)bh * S_ * DH;
    const __bf16* Vg = vt + (size_t)bh * DH * S_;
    bf16x8 qf[4];
#pragma unroll
    for (int kk = 0; kk < 4; ++kk)
        qf[kk] = *(const bf16x8*)&Qb[(size_t)(q0 + wid*16 + fr)*DH + kk*32 + (lane>>4)*8];
    float m[4] = {-3e38f, -3e38f, -3e38f, -3e38f};
    float l[4] = {0.f, 0.f, 0.f, 0.f};
    f32x4 o[8] = {};
    int rowb = q0 + wid*16 + (lane >> 4)*4;
    int nit = qb + 1;
    stage_kv(Kb, Vg, (char*)Ks, (char*)Vs, 0, t, wid);
    for (int it = 0; it < nit; ++it) {
        int kv0 = it * 64, cur = it & 1;
        float abv[4][4];
#pragma unroll
        for (int n = 0; n < 4; ++n)
#pragma unroll
            for (int r = 0; r < 4; ++r)
                abv[n][r] = ab[(size_t)(rowb + r)*S_ + kv0 + n*16 + fr];
        if (it + 1 < nit) {
            stage_kv(Kb, Vg, (char*)Ks + (cur^1)*16384, (char*)Vs + (cur^1)*16384,
                     kv0 + 64, t, wid);
            asm volatile("s_waitcnt vmcnt(8)" ::: "memory");
        } else {
            asm volatile("s_waitcnt vmcnt(0)" ::: "memory");
        }
        __builtin_amdgcn_s_barrier();
        const char* KsC = (const char*)Ks + cur*16384;
        float pv[4][4];
        __builtin_amdgcn_s_setprio(1);
#pragma unroll
        for (int n = 0; n < 4; ++n) {
            f32x4 sacc = {};
#pragma unroll
            for (int kk = 0; kk < 4; ++kk) {
                int row = n*16 + fr;
                int c2 = (kk*64 + fkb) ^ ((fr & 7) << 4);
                bf16x8 kf = *(const bf16x8*)(KsC + row*256 + c2);
                sacc = __builtin_amdgcn_mfma_f32_16x16x32_bf16(qf[kk], kf, sacc, 0, 0, 0);
            }
#pragma unroll
            for (int r = 0; r < 4; ++r) pv[n][r] = sacc[r];
        }
        __builtin_amdgcn_s_setprio(0);
#pragma unroll
        for (int n = 0; n < 4; ++n) {
            int col = kv0 + n*16 + fr;
#pragma unroll
            for (int r = 0; r < 4; ++r)
                pv[n][r] += abv[n][r] + (col <= rowb + r ? 0.f : -1e10f);
        }
        float alpha[4];
#pragma unroll
        for (int r = 0; r < 4; ++r) {
            float mx = fmaxf(fmaxf(pv[0][r], pv[1][r]), fmaxf(pv[2][r], pv[3][r]));
#pragma unroll
            for (int off = 8; off >= 1; off >>= 1) mx = fmaxf(mx, __shfl_xor(mx, off));
            float mn = fmaxf(m[r], mx);
            alpha[r] = __expf(m[r] - mn);
            m[r] = mn;
            float sum = 0.f;
#pragma unroll
            for (int n = 0; n < 4; ++n) { pv[n][r] = __expf(pv[n][r] - mn); sum += pv[n][r]; }
#pragma unroll
            for (int off = 8; off >= 1; off >>= 1) sum += __shfl_xor(sum, off);
            l[r] = l[r]*alpha[r] + sum;
        }
#pragma unroll
        for (int nf = 0; nf < 8; ++nf)
#pragma unroll
            for (int r = 0; r < 4; ++r) o[nf][r] *= alpha[r];
#pragma unroll
        for (int n = 0; n < 4; ++n)
#pragma unroll
            for (int r = 0; r < 4; ++r)
                Ps[wid][((lane >> 4)*4 + r)*72 + n*16 + fr] = (__bf16)pv[n][r];
        asm volatile("s_waitcnt lgkmcnt(0)" ::: "memory");
        __builtin_amdgcn_sched_barrier(0);
        bf16x8 pf[2];
#pragma unroll
        for (int kk = 0; kk < 2; ++kk)
            pf[kk] = *(const bf16x8*)&Ps[wid][fr*72 + kk*32 + (lane>>4)*8];
        const char* VsC = (const char*)Vs + cur*16384;
        __builtin_amdgcn_s_setprio(1);
#pragma unroll
        for (int nf = 0; nf < 8; ++nf) {
#pragma unroll
            for (int kk = 0; kk < 2; ++kk) {
                int row = nf*16 + fr;
                int c2 = (kk*64 + fkb) ^ ((fr & 7) << 4);
                bf16x8 vf = *(const bf16x8*)(VsC + row*128 + c2);
                o[nf] = __builtin_amdgcn_mfma_f32_16x16x32_bf16(pf[kk], vf, o[nf], 0, 0, 0);
            }
        }
        __builtin_amdgcn_s_setprio(0);
        asm volatile("s_waitcnt lgkmcnt(0)" ::: "memory");
        __builtin_amdgcn_sched_barrier(0);
        __builtin_amdgcn_s_barrier();
    }
    int rq = (lane >> 4) * 4;
#pragma unroll
    for (int r = 0; r < 4; ++r) {
        float inv = 1.f / l[r];
#pragma unroll
        for (int nf = 0; nf < 8; ++nf) {
            int qr = q0 + wid*16 + rq + r;
            int d = nf*16 + fr;
            ag[((size_t)(b*S_ + qr))*DOUT + hh*640 + d] = (__bf16)(o[nf][r] * inv);
        }
    }
}

extern "C" void kernel_launch(void* const* d_in, const int* in_sizes, int n_in,
                              void* d_out, int out_size, void* d_ws, size_t ws_size,
                              hipStream_t stream) {
    const float* x     = (const float*)d_in[0];
    const float* ab    = (const float*)d_in[1];
    const float* lns   = (const float*)d_in[2];
    const float* lno   = (const float*)d_in[3];
    const float* w_in  = (const float*)d_in[4];
    const float* b_in  = (const float*)d_in[5];
    const float* w_out = (const float*)d_in[6];
    const float* b_out = (const float*)d_in[7];
    float* out = (float*)d_out;
    char* ws = (char*)d_ws;

    __bf16* w_in_t  = (__bf16*)(ws);                 //         0: 11264x1024 bf16
    __bf16* w_out_t = (__bf16*)(ws +  23068672);     //  23068672: 1024x5120 bf16
    __bf16* hbuf    = (__bf16*)(ws +  33554432);     //  33554432: 4096x1024 bf16
    __bf16* proj2   = (__bf16*)(ws +  41943040);     //  41943040: 4096x3072 bf16
    __bf16* vtb     = (__bf16*)(ws +  67108864);     //  67108864: 16x128x2048 bf16
    __bf16* qh      = (__bf16*)(ws +  75497472);
    __bf16* kh      = (__bf16*)(ws +  83886080);
    __bf16* agb     = (__bf16*)(ws +  92274688);     //  92274688: 4096x5120 bf16
    __bf16* pkb     = (__bf16*)(ws + 134217728);     // 134217728: 8 x 4096x1024 bf16 (67MB)
    float*  bperm   = (float*)(ws + 134217728);      // reuses pkb region (GEMM1 phase only)

    transpose_perm_kernel<<<dim3(FIN/64, DM/64), 256, 0, stream>>>(w_in, w_in_t);
    transpose_kernel<<<dim3(DM/64, DOUT/64), 256, 0, stream>>>(w_out, w_out_t, DOUT, DM);
    permbias_kernel<<<(FIN + 255)/256, 256, 0, stream>>>(b_in, bperm);
    ln_kernel<<<ROWS, 256, 0, stream>>>(x, lns, lno, hbuf);
    gemm256s_kernel<<<dim3(FIN/256, ROWS/256, 1), 512, 0, stream>>>(hbuf, w_in_t, bperm,
                                                                    proj2, agb, nullptr,
                                                                    ROWS, FIN, DM, DM);
    rqkv_kernel<<<dim3(ROWS/64, NSH), 256, 0, stream>>>(proj2, qh, kh, vtb);
    attn_kernel<<<dim3(S_/64, B_*NSH), 256, 0, stream>>>(qh, kh, vtb, ab, agb);
    gemm256s_kernel<<<dim3(DM/256, ROWS/256, 8), 512, 0, stream>>>(agb, w_out_t, nullptr,
                                                                   nullptr, nullptr, pkb,
                                                                   ROWS, DM, DOUT, DOUT/8);
    addbias8_kernel<<<ROWS*DM/1024, 256, 0, stream>>>(pkb, b_out, out);
}

// Round 11
// 287.175 us; speedup vs baseline: 5.8072x; 5.8072x over previous
//
#include <hip/hip_runtime.h>
#include <stdint.h>

#define B_   2
#define S_   2048
#define DM   1024
#define FIN  11264
#define DOUT 5120
#define NSH  8
#define DH   128
#define ROWS (B_*S_)

typedef __attribute__((ext_vector_type(8))) __bf16 bf16x8;
typedef __attribute__((ext_vector_type(4))) __bf16 bf16x4;
typedef __attribute__((ext_vector_type(4))) float  f32x4;

union U2 { unsigned int u; __bf16 h[2]; };

__device__ __forceinline__ void gload16(const void* g, void* l) {
    __builtin_amdgcn_global_load_lds((const __attribute__((address_space(1))) void*)g,
                                     (__attribute__((address_space(3))) void*)l, 16, 0, 0);
}

// column permutation: newcol -> original w_in column
__device__ __forceinline__ int origcol(int c) {
    if (c < 3072) { int p = c / 384; return p*1408 + (c - p*384); }
    int q = c - 3072; int p = q >> 10; int w = q & 1023;
    int a = w >> 5, g = (w >> 4) & 1, u = w & 15;
    return p*1408 + 384 + g*512 + a*16 + u;
}

// ---------------- LayerNorm: x f32 (ROWS x DM) -> h bf16 ----------------
__global__ __launch_bounds__(256) void ln_kernel(const float* __restrict__ x,
                                                 const float* __restrict__ sc,
                                                 const float* __restrict__ of,
                                                 __bf16* __restrict__ h) {
    int row = blockIdx.x, t = threadIdx.x;
    const float4 v = *(const float4*)&x[(size_t)row*DM + t*4];
    float s  = v.x + v.y + v.z + v.w;
    float ss = v.x*v.x + v.y*v.y + v.z*v.z + v.w*v.w;
#pragma unroll
    for (int off = 32; off >= 1; off >>= 1) {
        s  += __shfl_xor(s, off);
        ss += __shfl_xor(ss, off);
    }
    __shared__ float rs_[4], rss_[4];
    int wid = t >> 6, lane = t & 63;
    if (lane == 0) { rs_[wid] = s; rss_[wid] = ss; }
    __syncthreads();
    s  = rs_[0] + rs_[1] + rs_[2] + rs_[3];
    ss = rss_[0] + rss_[1] + rss_[2] + rss_[3];
    float mu  = s * (1.f/DM);
    float var = ss * (1.f/DM) - mu*mu;
    float r   = rsqrtf(var + 1e-5f);
    float4 scv = *(const float4*)&sc[t*4];
    float4 ofv = *(const float4*)&of[t*4];
    bf16x4 o;
    o[0] = (__bf16)((v.x-mu)*r*scv.x + ofv.x);
    o[1] = (__bf16)((v.y-mu)*r*scv.y + ofv.y);
    o[2] = (__bf16)((v.z-mu)*r*scv.z + ofv.z);
    o[3] = (__bf16)((v.w-mu)*r*scv.w + ofv.w);
    *(bf16x4*)&h[(size_t)row*DM + t*4] = o;
}

// ------------- transpose+cast: in R x C f32 -> out C x R bf16 (plain) -----------
__global__ __launch_bounds__(256) void transpose_kernel(const float* __restrict__ in,
                                                        __bf16* __restrict__ out,
                                                        int R, int C) {
    __shared__ __bf16 tile[64][72];
    int c0 = blockIdx.x * 64, r0 = blockIdx.y * 64;
    int t = threadIdx.x;
#pragma unroll
    for (int it = 0; it < 4; ++it) {
        int flat = it*1024 + t*4;
        int rl = flat >> 6, cl = flat & 63;
        float4 v = *(const float4*)&in[(size_t)(r0+rl)*C + c0 + cl];
        tile[rl][cl+0] = (__bf16)v.x;
        tile[rl][cl+1] = (__bf16)v.y;
        tile[rl][cl+2] = (__bf16)v.z;
        tile[rl][cl+3] = (__bf16)v.w;
    }
    __syncthreads();
#pragma unroll
    for (int it = 0; it < 4; ++it) {
        int flat = it*1024 + t*4;
        int cl = flat >> 6, rl = flat & 63;
        bf16x4 o;
#pragma unroll
        for (int j = 0; j < 4; ++j) o[j] = tile[rl+j][cl];
        *(bf16x4*)&out[(size_t)(c0+cl)*R + r0 + rl] = o;
    }
}

// ------- transpose+cast with column permutation: w_in (DM x FIN) -> w_in_t [newcol][DM] -------
__global__ __launch_bounds__(256) void transpose_perm_kernel(const float* __restrict__ in,
                                                             __bf16* __restrict__ out) {
    __shared__ __bf16 tile[64][72];
    int c0 = blockIdx.x * 64, r0 = blockIdx.y * 64;
    int t = threadIdx.x;
#pragma unroll
    for (int it = 0; it < 4; ++it) {
        int flat = it*1024 + t*4;
        int rl = flat >> 6, cl = flat & 63;
        int oc = origcol(c0 + cl);
        float4 v = *(const float4*)&in[(size_t)(r0+rl)*FIN + oc];
        tile[rl][cl+0] = (__bf16)v.x;
        tile[rl][cl+1] = (__bf16)v.y;
        tile[rl][cl+2] = (__bf16)v.z;
        tile[rl][cl+3] = (__bf16)v.w;
    }
    __syncthreads();
#pragma unroll
    for (int it = 0; it < 4; ++it) {
        int flat = it*1024 + t*4;
        int cl = flat >> 6, rl = flat & 63;
        bf16x4 o;
#pragma unroll
        for (int j = 0; j < 4; ++j) o[j] = tile[rl+j][cl];
        *(bf16x4*)&out[(size_t)(c0+cl)*DM + r0 + rl] = o;
    }
}

// ---------------- permuted bias ----------------
__global__ __launch_bounds__(256) void permbias_kernel(const float* __restrict__ b_in,
                                                       float* __restrict__ bp) {
    int c = blockIdx.x * 256 + threadIdx.x;
    if (c < FIN) bp[c] = b_in[origcol(c)];
}

// ============ GEMM1: 256x256 deep-flight dbuf, fused qvk/GLU epilogue ============
#define MFMA4(ACCI, BN) \
    acc[ACCI][BN] = __builtin_amdgcn_mfma_f32_16x16x32_bf16(a[(ACCI)&3][0], b[BN][0], acc[ACCI][BN],0,0,0); \
    acc[ACCI][BN] = __builtin_amdgcn_mfma_f32_16x16x32_bf16(a[(ACCI)&3][1], b[BN][1], acc[ACCI][BN],0,0,0);

__global__ __launch_bounds__(512, 2) void gemm1_kernel(const __bf16* __restrict__ A,
                                                       const __bf16* __restrict__ BT,
                                                       const float* __restrict__ bias,
                                                       __bf16* __restrict__ Cqvk,
                                                       __bf16* __restrict__ Cglu) {
    const int M = ROWS, N = FIN, K = DM;
    __shared__ __align__(16) char lds[131072];
    int t = threadIdx.x, wid = t >> 6, lane = t & 63;
    int wr = wid >> 2, wc = wid & 3;
    int fr = lane & 15, fq = lane >> 4;
    int nbx = gridDim.x;
    int bid = blockIdx.y * nbx + blockIdx.x;
    int cpx = (nbx * gridDim.y) >> 3;
    int swz = (bid & 7) * cpx + (bid >> 3);
    int bx = swz % nbx, by = swz / nbx;
    int m0 = by * 256, n0 = bx * 256;

    const __bf16* srcA[4];
    const __bf16* srcB[4];
#pragma unroll
    for (int j = 0; j < 4; ++j) {
        int F = (j*512 + t) * 16;
        int lr = F >> 7, c = (F & 127) ^ ((lr & 7) << 4);
        srcA[j] = A + (size_t)(m0 + lr) * K + (c >> 1);
        int row = ((lr >> 5) & 3) * 64 + (lr >> 7) * 32 + (lr & 31);
        srcB[j] = BT + (size_t)(n0 + row) * K + (c >> 1);
    }
    int lrAlo[4], lrAhi[4], lrB[4];
#pragma unroll
    for (int i = 0; i < 4; ++i) {
        lrAlo[i] = (wr*128 + i*16 + fr) * 128;
        lrAhi[i] = lrAlo[i] + 64*128;
    }
#pragma unroll
    for (int n = 0; n < 4; ++n)
        lrB[n] = ((n >> 1)*128 + wc*32 + (n & 1)*16 + fr) * 128;
    int swzb = (fr & 7) << 4;
    int cb00 = (fq*16) ^ swzb;
    int cb01 = (64 + fq*16) ^ swzb;

    f32x4 acc[8][4] = {};
    gload16(srcA[0], lds +     0 + wid*1024);
    gload16(srcA[2], lds + 16384 + wid*1024);
    gload16(srcB[0], lds + 32768 + wid*1024);
    gload16(srcB[1], lds + 40960 + wid*1024);
    gload16(srcB[2], lds + 49152 + wid*1024);
    gload16(srcB[3], lds + 57344 + wid*1024);
    gload16(srcA[1], lds +  8192 + wid*1024);
    gload16(srcA[3], lds + 24576 + wid*1024);
    asm volatile("s_waitcnt vmcnt(4)" ::: "memory");
    __builtin_amdgcn_s_barrier();

    int nit = K >> 6;
    for (int it = 0; it < nit; ++it) {
        const char* bc = lds + (it & 1) * 65536;
        char* bn = lds + ((it & 1) ^ 1) * 65536;
        const char* bcB = bc + 32768;
        int koff = (it + 1) << 6;
        bool pf = (it + 1 < nit);
        bf16x8 a[4][2], b[4][2];
        // P0
#pragma unroll
        for (int i = 0; i < 4; ++i) {
            a[i][0] = *(const bf16x8*)(bc + lrAlo[i] + cb00);
            a[i][1] = *(const bf16x8*)(bc + lrAlo[i] + cb01);
        }
        b[0][0] = *(const bf16x8*)(bcB + lrB[0] + cb00);
        b[0][1] = *(const bf16x8*)(bcB + lrB[0] + cb01);
        b[1][0] = *(const bf16x8*)(bcB + lrB[1] + cb00);
        b[1][1] = *(const bf16x8*)(bcB + lrB[1] + cb01);
        if (pf) {
            gload16(srcA[0] + koff, bn +     0 + wid*1024);
            gload16(srcA[2] + koff, bn + 16384 + wid*1024);
            gload16(srcB[0] + koff, bn + 32768 + wid*1024);
            gload16(srcB[1] + koff, bn + 40960 + wid*1024);
            gload16(srcB[2] + koff, bn + 49152 + wid*1024);
            gload16(srcB[3] + koff, bn + 57344 + wid*1024);
            gload16(srcA[1] + koff, bn +  8192 + wid*1024);
            gload16(srcA[3] + koff, bn + 24576 + wid*1024);
        }
        __builtin_amdgcn_s_setprio(1);
#pragma unroll
        for (int i = 0; i < 4; ++i) { MFMA4(i,0) MFMA4(i,1) }
        __builtin_amdgcn_s_setprio(0);
        if (pf) asm volatile("s_waitcnt vmcnt(10)" ::: "memory");
        else    asm volatile("s_waitcnt vmcnt(2)" ::: "memory");
        __builtin_amdgcn_s_barrier();
        // P1
        b[2][0] = *(const bf16x8*)(bcB + lrB[2] + cb00);
        b[2][1] = *(const bf16x8*)(bcB + lrB[2] + cb01);
        b[3][0] = *(const bf16x8*)(bcB + lrB[3] + cb00);
        b[3][1] = *(const bf16x8*)(bcB + lrB[3] + cb01);
        __builtin_amdgcn_s_setprio(1);
#pragma unroll
        for (int i = 0; i < 4; ++i) { MFMA4(i,2) MFMA4(i,3) }
        __builtin_amdgcn_s_setprio(0);
        if (pf) asm volatile("s_waitcnt vmcnt(8)" ::: "memory");
        else    asm volatile("s_waitcnt vmcnt(0)" ::: "memory");
        __builtin_amdgcn_s_barrier();
        // P2
#pragma unroll
        for (int i = 0; i < 4; ++i) {
            a[i][0] = *(const bf16x8*)(bc + lrAhi[i] + cb00);
            a[i][1] = *(const bf16x8*)(bc + lrAhi[i] + cb01);
        }
        __builtin_amdgcn_s_setprio(1);
#pragma unroll
        for (int i = 0; i < 4; ++i) { MFMA4(4+i,0) MFMA4(4+i,1) MFMA4(4+i,2) MFMA4(4+i,3) }
        __builtin_amdgcn_s_setprio(0);
        if (pf) {
            asm volatile("s_waitcnt vmcnt(4)" ::: "memory");
            __builtin_amdgcn_s_barrier();
        }
    }
    // ---------------- fused epilogues ----------------
    if (n0 < 3072) {
#pragma unroll
        for (int i = 0; i < 8; ++i)
#pragma unroll
            for (int n = 0; n < 4; ++n) {
                int col = n0 + wc*64 + (n >> 1)*32 + (n & 1)*16 + fr;
                float bv = bias[col];
#pragma unroll
                for (int r = 0; r < 4; ++r) {
                    int row = m0 + wr*128 + i*16 + fq*4 + r;
                    Cqvk[(size_t)row*3072 + col] = (__bf16)(acc[i][n][r] + bv);
                }
            }
    } else {
        int q = n0 - 3072;
        int p = q >> 10;
#pragma unroll
        for (int m = 0; m < 2; ++m) {
            int off = wc*64 + m*32;
            float bo = bias[n0 + off + fr];
            float bg = bias[n0 + off + 16 + fr];
            int j = (((q & 1023) + off) >> 5) * 16 + fr;
            int colg = p*640 + 128 + j;
#pragma unroll
            for (int i = 0; i < 8; ++i)
#pragma unroll
                for (int r = 0; r < 4; ++r) {
                    int row = m0 + wr*128 + i*16 + fq*4 + r;
                    float ov = acc[i][2*m][r] + bo;
                    float gv = acc[i][2*m+1][r] + bg;
                    float e2 = __expf(1.5957691216057308f*(gv + 0.044715f*gv*gv*gv));
                    float gl = gv * (1.f - 1.f/(e2 + 1.f));
                    Cglu[(size_t)row*DOUT + colg] = (__bf16)(ov * gl);
                }
        }
    }
}

// ======== GEMM2: 128x128 single-buffered, 4 blocks/CU, split-K f32 partials ========
__global__ __launch_bounds__(256, 4) void gemm2_kernel(const __bf16* __restrict__ A,
                                                       const __bf16* __restrict__ BT,
                                                       float* __restrict__ P,
                                                       int klen) {
    const int M = ROWS, N = DM, K = DOUT;
    __shared__ __align__(16) char lds[32768];
    int t = threadIdx.x, wid = t >> 6, lane = t & 63;
    int wm = (wid >> 1) * 64, wn = (wid & 1) * 64;
    int fr = lane & 15, fq = lane >> 4;
    int kbeg = blockIdx.z * klen;
    int nbx = gridDim.x;
    int bid = blockIdx.y * nbx + blockIdx.x;
    int cpx = (nbx * gridDim.y) >> 3;
    int swz = (bid & 7) * cpx + (bid >> 3);
    int bx = swz % nbx, by = swz / nbx;
    int m0 = by * 128, n0 = bx * 128;

    const __bf16* srcA[4];
    const __bf16* srcB[4];
#pragma unroll
    for (int j = 0; j < 4; ++j) {
        int F = (j*256 + t) * 16;
        int row = F >> 7;
        int c = (F & 127) ^ ((row & 7) << 4);
        srcA[j] = A  + (size_t)(m0 + row) * K + kbeg + (c >> 1);
        srcB[j] = BT + (size_t)(n0 + row) * K + kbeg + (c >> 1);
    }
    int rowA[4], rowB[4];
#pragma unroll
    for (int i = 0; i < 4; ++i) {
        rowA[i] = (wm + i*16 + fr) * 128;
        rowB[i] = 16384 + (wn + i*16 + fr) * 128;
    }
    int swzb = (fr & 7) << 4;
    int cb0 = (fq*16) ^ swzb;
    int cb1 = (64 + fq*16) ^ swzb;

    f32x4 acc[4][4] = {};
    for (int k0 = 0; k0 < klen; k0 += 64) {
#pragma unroll
        for (int j = 0; j < 4; ++j)
            gload16(srcA[j] + k0, lds + j*4096 + wid*1024);
#pragma unroll
        for (int j = 0; j < 4; ++j)
            gload16(srcB[j] + k0, lds + 16384 + j*4096 + wid*1024);
        __syncthreads();
        bf16x8 a[4], b[4];
#pragma unroll
        for (int i = 0; i < 4; ++i) a[i] = *(const bf16x8*)(lds + rowA[i] + cb0);
#pragma unroll
        for (int n = 0; n < 4; ++n) b[n] = *(const bf16x8*)(lds + rowB[n] + cb0);
#pragma unroll
        for (int i = 0; i < 4; ++i)
#pragma unroll
            for (int n = 0; n < 4; ++n)
                acc[i][n] = __builtin_amdgcn_mfma_f32_16x16x32_bf16(a[i], b[n], acc[i][n], 0, 0, 0);
#pragma unroll
        for (int i = 0; i < 4; ++i) a[i] = *(const bf16x8*)(lds + rowA[i] + cb1);
#pragma unroll
        for (int n = 0; n < 4; ++n) b[n] = *(const bf16x8*)(lds + rowB[n] + cb1);
#pragma unroll
        for (int i = 0; i < 4; ++i)
#pragma unroll
            for (int n = 0; n < 4; ++n)
                acc[i][n] = __builtin_amdgcn_mfma_f32_16x16x32_bf16(a[i], b[n], acc[i][n], 0, 0, 0);
        __syncthreads();
    }
    float* Pz = P + (size_t)blockIdx.z * M * N;
#pragma unroll
    for (int i = 0; i < 4; ++i)
#pragma unroll
        for (int n = 0; n < 4; ++n) {
            int col = n0 + wn + n*16 + fr;
#pragma unroll
            for (int r = 0; r < 4; ++r) {
                int row = m0 + wm + i*16 + fq*4 + r;
                Pz[(size_t)row*N + col] = acc[i][n][r];
            }
        }
}

// ---------------- out = p0 + p1 + bias (f32) ----------------
__global__ __launch_bounds__(256) void addbias2_kernel(const float* __restrict__ pk,
                                                       const float* __restrict__ bias,
                                                       float* __restrict__ out) {
    int idx = blockIdx.x * 256 + threadIdx.x;
    const size_t stride = (size_t)ROWS * DM / 4;
    float4 a0 = ((const float4*)pk)[idx];
    float4 a1 = ((const float4*)pk)[idx + stride];
    float4 bb = ((const float4*)bias)[idx & 255];
    float4 o;
    o.x = a0.x + a1.x + bb.x;
    o.y = a0.y + a1.y + bb.y;
    o.z = a0.z + a1.z + bb.z;
    o.w = a0.w + a1.w + bb.w;
    ((float4*)out)[idx] = o;
}

// ==== fused rope + split + V-transpose: proj2 [ROWS][3072] -> qh, kh, vt ====
__global__ __launch_bounds__(256) void rqkv_kernel(const __bf16* __restrict__ proj2,
                                                   __bf16* __restrict__ qh,
                                                   __bf16* __restrict__ kh,
                                                   __bf16* __restrict__ vt) {
    __shared__ __bf16 tile[64*144];
    int r0 = blockIdx.x * 64;
    int p  = blockIdx.y;
    int t  = threadIdx.x;
    int b  = r0 >> 11;
    int bh = b*NSH + p;
#pragma unroll
    for (int j = 0; j < 4; ++j) {
        int e = (j*256 + t) * 8;
        int sl = e >> 7, d = e & 127;
        const __bf16* rowp = proj2 + (size_t)(r0 + sl)*3072 + p*384;
        bf16x8 vq = *(const bf16x8*)&rowp[d];
        bf16x8 vv = *(const bf16x8*)&rowp[128 + d];
        bf16x8 vk = *(const bf16x8*)&rowp[256 + d];
        int s = (r0 + sl) & (S_ - 1);
        if (d < 64) {
#pragma unroll
            for (int u = 0; u < 4; ++u) {
                int i = (d >> 1) + u;
                float inv = exp2f(-(float)i * 0.4152410118609203f);
                float ang = (float)s * inv;
                float cn = __cosf(ang), sn = __sinf(ang);
                float q0 = vq[2*u], q1 = vq[2*u+1];
                float k0 = vk[2*u], k1 = vk[2*u+1];
                vq[2*u]   = (__bf16)(q0*cn - q1*sn);
                vq[2*u+1] = (__bf16)(q1*cn + q0*sn);
                vk[2*u]   = (__bf16)(k0*cn - k1*sn);
                vk[2*u+1] = (__bf16)(k1*cn + k0*sn);
            }
        }
#pragma unroll
        for (int u = 0; u < 8; ++u) vq[u] = (__bf16)((float)vq[u] * 0.125f);
        size_t o = ((size_t)bh * S_ + s) * DH + d;
        *(bf16x8*)&qh[o] = vq;
        *(bf16x8*)&kh[o] = vk;
        int ch = ((d >> 3) + sl) & 15;
        *(bf16x8*)&tile[sl*144 + ch*8] = vv;
    }
    __syncthreads();
#pragma unroll
    for (int j = 0; j < 4; ++j) {
        int e = (j*256 + t) * 8;
        int d = e >> 6, sb = e & 63;
        bf16x8 o;
#pragma unroll
        for (int u = 0; u < 8; ++u) {
            int sl = sb + u;
            int ch = ((d >> 3) + sl) & 15;
            o[u] = tile[sl*144 + ch*8 + (d & 7)];
        }
        size_t ov = ((size_t)bh * DH + d) * S_ + (r0 & (S_ - 1)) + sb;
        *(bf16x8*)&vt[ov] = o;
    }
}

// ---------------------- flash attention, causal + bias ----------------------
__device__ __forceinline__ void stage_kv(const __bf16* Kb, const __bf16* Vg,
                                         char* KsB, char* VsB,
                                         int kvbase, int t, int wid) {
#pragma unroll
    for (int j = 0; j < 4; ++j) {
        int F = (j*256 + t)*16;
        int r = F >> 8, c = F & 255;
        gload16(Kb + (size_t)(kvbase + r)*DH + ((c ^ ((r & 7) << 4)) >> 1),
                KsB + j*4096 + (wid << 10));
    }
#pragma unroll
    for (int j = 0; j < 4; ++j) {
        int F = (j*256 + t)*16;
        int r = F >> 7, c = F & 127;
        gload16(Vg + (size_t)r*S_ + kvbase + ((c ^ ((r & 7) << 4)) >> 1),
                VsB + j*4096 + (wid << 10));
    }
}

__global__ __launch_bounds__(256, 2) void attn_kernel(const __bf16* __restrict__ qh,
                                                      const __bf16* __restrict__ kh,
                                                      const __bf16* __restrict__ vt,
                                                      const float* __restrict__ ab,
                                                      __bf16* __restrict__ ag) {
    __shared__ __bf16 Ks[2*8192];
    __shared__ __bf16 Vs[2*8192];
    __shared__ __bf16 Ps[4][16*72];
    int bh = blockIdx.y;
    int b = bh >> 3, hh = bh & 7;
    int xr = blockIdx.x;
    int qb = (xr & 1) ? (31 - (xr >> 1)) : (xr >> 1);
    int q0 = qb * 64;
    int t = threadIdx.x, wid = t >> 6, lane = t & 63;
    int fr = lane & 15, fkb = (lane >> 4) * 16;
    const __bf16* Qb = qh + (size_t)bh * S_ * DH;
    const __bf16* Kb = kh + (size_t)bh * S_ * DH;
    const __bf16* Vg = vt + (size_t)bh * DH * S_;
    bf16x8 qf[4];
#pragma unroll
    for (int kk = 0; kk < 4; ++kk)
        qf[kk] = *(const bf16x8*)&Qb[(size_t)(q0 + wid*16 + fr)*DH + kk*32 + (lane>>4)*8];
    float m[4] = {-3e38f, -3e38f, -3e38f, -3e38f};
    float l[4] = {0.f, 0.f, 0.f, 0.f};
    f32x4 o[8] = {};
    int rowb = q0 + wid*16 + (lane >> 4)*4;
    int nit = qb + 1;
    stage_kv(Kb, Vg, (char*)Ks, (char*)Vs, 0, t, wid);
    for (int it = 0; it < nit; ++it) {
        int kv0 = it * 64, cur = it & 1;
        float abv[4][4];
#pragma unroll
        for (int n = 0; n < 4; ++n)
#pragma unroll
            for (int r = 0; r < 4; ++r)
                abv[n][r] = ab[(size_t)(rowb + r)*S_ + kv0 + n*16 + fr];
        if (it + 1 < nit) {
            stage_kv(Kb, Vg, (char*)Ks + (cur^1)*16384, (char*)Vs + (cur^1)*16384,
                     kv0 + 64, t, wid);
            asm volatile("s_waitcnt vmcnt(8)" ::: "memory");
        } else {
            asm volatile("s_waitcnt vmcnt(0)" ::: "memory");
        }
        __builtin_amdgcn_s_barrier();
        const char* KsC = (const char*)Ks + cur*16384;
        float pv[4][4];
        __builtin_amdgcn_s_setprio(1);
#pragma unroll
        for (int n = 0; n < 4; ++n) {
            f32x4 sacc = {};
#pragma unroll
            for (int kk = 0; kk < 4; ++kk) {
                int row = n*16 + fr;
                int c2 = (kk*64 + fkb) ^ ((fr & 7) << 4);
                bf16x8 kf = *(const bf16x8*)(KsC + row*256 + c2);
                sacc = __builtin_amdgcn_mfma_f32_16x16x32_bf16(qf[kk], kf, sacc, 0, 0, 0);
            }
#pragma unroll
            for (int r = 0; r < 4; ++r) pv[n][r] = sacc[r];
        }
        __builtin_amdgcn_s_setprio(0);
#pragma unroll
        for (int n = 0; n < 4; ++n) {
            int col = kv0 + n*16 + fr;
#pragma unroll
            for (int r = 0; r < 4; ++r)
                pv[n][r] += abv[n][r] + (col <= rowb + r ? 0.f : -1e10f);
        }
        float alpha[4];
#pragma unroll
        for (int r = 0; r < 4; ++r) {
            float mx = fmaxf(fmaxf(pv[0][r], pv[1][r]), fmaxf(pv[2][r], pv[3][r]));
#pragma unroll
            for (int off = 8; off >= 1; off >>= 1) mx = fmaxf(mx, __shfl_xor(mx, off));
            float mn = fmaxf(m[r], mx);
            alpha[r] = __expf(m[r] - mn);
            m[r] = mn;
            float sum = 0.f;
#pragma unroll
            for (int n = 0; n < 4; ++n) { pv[n][r] = __expf(pv[n][r] - mn); sum += pv[n][r]; }
#pragma unroll
            for (int off = 8; off >= 1; off >>= 1) sum += __shfl_xor(sum, off);
            l[r] = l[r]*alpha[r] + sum;
        }
#pragma unroll
        for (int nf = 0; nf < 8; ++nf)
#pragma unroll
            for (int r = 0; r < 4; ++r) o[nf][r] *= alpha[r];
#pragma unroll
        for (int n = 0; n < 4; ++n)
#pragma unroll
            for (int r = 0; r < 4; ++r)
                Ps[wid][((lane >> 4)*4 + r)*72 + n*16 + fr] = (__bf16)pv[n][r];
        asm volatile("s_waitcnt lgkmcnt(0)" ::: "memory");
        __builtin_amdgcn_sched_barrier(0);
        bf16x8 pf[2];
#pragma unroll
        for (int kk = 0; kk < 2; ++kk)
            pf[kk] = *(const bf16x8*)&Ps[wid][fr*72 + kk*32 + (lane>>4)*8];
        const char* VsC = (const char*)Vs + cur*16384;
        __builtin_amdgcn_s_setprio(1);
#pragma unroll
        for (int nf = 0; nf < 8; ++nf) {
#pragma unroll
            for (int kk = 0; kk < 2; ++kk) {
                int row = nf*16 + fr;
                int c2 = (kk*64 + fkb) ^ ((fr & 7) << 4);
                bf16x8 vf = *(const bf16x8*)(VsC + row*128 + c2);
                o[nf] = __builtin_amdgcn_mfma_f32_16x16x32_bf16(pf[kk], vf, o[nf], 0, 0, 0);
            }
        }
        __builtin_amdgcn_s_setprio(0);
        asm volatile("s_waitcnt lgkmcnt(0)" ::: "memory");
        __builtin_amdgcn_sched_barrier(0);
        __builtin_amdgcn_s_barrier();
    }
    int rq = (lane >> 4) * 4;
#pragma unroll
    for (int r = 0; r < 4; ++r) {
        float inv = 1.f / l[r];
#pragma unroll
        for (int nf = 0; nf < 8; ++nf) {
            int qr = q0 + wid*16 + rq + r;
            int d = nf*16 + fr;
            ag[((size_t)(b*S_ + qr))*DOUT + hh*640 + d] = (__bf16)(o[nf][r] * inv);
        }
    }
}

extern "C" void kernel_launch(void* const* d_in, const int* in_sizes, int n_in,
                              void* d_out, int out_size, void* d_ws, size_t ws_size,
                              hipStream_t stream) {
    const float* x     = (const float*)d_in[0];
    const float* ab    = (const float*)d_in[1];
    const float* lns   = (const float*)d_in[2];
    const float* lno   = (const float*)d_in[3];
    const float* w_in  = (const float*)d_in[4];
    const float* b_in  = (const float*)d_in[5];
    const float* w_out = (const float*)d_in[6];
    const float* b_out = (const float*)d_in[7];
    float* out = (float*)d_out;
    char* ws = (char*)d_ws;

    __bf16* w_in_t  = (__bf16*)(ws);                 //         0: 11264x1024 bf16
    __bf16* w_out_t = (__bf16*)(ws +  23068672);     //  23068672: 1024x5120 bf16
    __bf16* hbuf    = (__bf16*)(ws +  33554432);     //  33554432: 4096x1024 bf16
    __bf16* proj2   = (__bf16*)(ws +  41943040);     //  41943040: 4096x3072 bf16
    __bf16* vtb     = (__bf16*)(ws +  67108864);     //  67108864: 16x128x2048 bf16
    __bf16* qh      = (__bf16*)(ws +  75497472);
    __bf16* kh      = (__bf16*)(ws +  83886080);
    __bf16* agb     = (__bf16*)(ws +  92274688);     //  92274688: 4096x5120 bf16
    float*  pk      = (float*)(ws + 134217728);      // 134217728: 2 x 4096x1024 f32 (33.5MB)
    float*  bperm   = (float*)(ws + 167772160);      // separate region (no aliasing)

    transpose_perm_kernel<<<dim3(FIN/64, DM/64), 256, 0, stream>>>(w_in, w_in_t);
    transpose_kernel<<<dim3(DM/64, DOUT/64), 256, 0, stream>>>(w_out, w_out_t, DOUT, DM);
    permbias_kernel<<<(FIN + 255)/256, 256, 0, stream>>>(b_in, bperm);
    ln_kernel<<<ROWS, 256, 0, stream>>>(x, lns, lno, hbuf);
    gemm1_kernel<<<dim3(FIN/256, ROWS/256), 512, 0, stream>>>(hbuf, w_in_t, bperm,
                                                              proj2, agb);
    rqkv_kernel<<<dim3(ROWS/64, NSH), 256, 0, stream>>>(proj2, qh, kh, vtb);
    attn_kernel<<<dim3(S_/64, B_*NSH), 256, 0, stream>>>(qh, kh, vtb, ab, agb);
    gemm2_kernel<<<dim3(DM/128, ROWS/128, 2), 256, 0, stream>>>(agb, w_out_t, pk, DOUT/2);
    addbias2_kernel<<<ROWS*DM/1024, 256, 0, stream>>>(pk, b_out, out);
}